// Round 8
// baseline (3307.359 us; speedup 1.0000x reference)
//
#include <hip/hip_runtime.h>

typedef __bf16 bf16;
typedef __attribute__((ext_vector_type(4))) __bf16 bf16x4;
typedef __attribute__((ext_vector_type(8))) __bf16 bf16x8;
typedef __attribute__((ext_vector_type(4))) float f32x4;
typedef __attribute__((ext_vector_type(4))) _Float16 f16x4;
typedef __attribute__((ext_vector_type(2))) _Float16 f16x2;

#define B_   2
#define L_   1024
#define DM_  512
#define H_   8
#define D_   64
#define PD_  64
#define NEG_VAL -10000.0f

#define XB_N   (2048*512)
#define WT_N   (1536*512)
#define WTO_N  (512*512)
#define WTPB_N (16*64)

// MEASUREMENT ROUND: idempotent repeat counts to surface attn/out in top-5
// with counters, and to give exact per-rep times. Functional output identical.
#define REP_ATTN 40
#define REP_OUT  100

static __device__ __forceinline__ f32x4 mfma_bf16(bf16x8 a, bf16x8 b, f32x4 c) {
  return __builtin_amdgcn_mfma_f32_16x16x32_bf16(a, b, c, 0, 0, 0);
}

// ---------------- prep: convert & transpose weights, convert x ----------------
__global__ __launch_bounds__(256) void prep_kernel(
    const float* __restrict__ x, const float* __restrict__ Wq, const float* __restrict__ Wk,
    const float* __restrict__ Wv, const float* __restrict__ Wo, const float* __restrict__ Wpb,
    bf16* __restrict__ xb, bf16* __restrict__ Wt, bf16* __restrict__ Wto, bf16* __restrict__ Wtpb) {
  const int total = XB_N + WT_N + WTO_N + WTPB_N;
  for (int idx = blockIdx.x * 256 + threadIdx.x; idx < total; idx += gridDim.x * 256) {
    if (idx < XB_N) {
      xb[idx] = (bf16)x[idx];
    } else if (idx < XB_N + WT_N) {
      int t = idx - XB_N;
      int n = t >> 9, kk = t & 511;       // Wt[n][k]
      int sel = n >> 9, nn = n & 511;
      const float* W = sel == 0 ? Wq : (sel == 1 ? Wk : Wv);
      Wt[t] = (bf16)W[kk * 512 + nn];
    } else if (idx < XB_N + WT_N + WTO_N) {
      int t = idx - XB_N - WT_N;
      int n = t >> 9, kk = t & 511;
      Wto[t] = (bf16)Wo[kk * 512 + n];
    } else {
      int t = idx - XB_N - WT_N - WTO_N;
      int n = t >> 6, kk = t & 63;
      Wtpb[t] = (n < 8) ? (bf16)Wpb[kk * 8 + n] : (bf16)0.0f;
    }
  }
}

// ---------------- qkv: xb(2048x512) @ Wt^T -> q,k bf16 [b][h][l][d], vT bf16 [b][h][d][l] ----------------
__global__ __launch_bounds__(256) void qkv_gemm(
    const bf16* __restrict__ xb, const bf16* __restrict__ Wt,
    const float* __restrict__ bq, const float* __restrict__ bk, const float* __restrict__ bv,
    bf16* __restrict__ qb, bf16* __restrict__ kb, bf16* __restrict__ vT) {
  int wid = blockIdx.x * 4 + (threadIdx.x >> 6);
  int lane = threadIdx.x & 63;
  int mt = wid / 48, nt = wid - mt * 48;   // 64 x 48 tiles of 32x32
  int row0 = mt * 32, col0 = nt * 32;
  int lr = lane & 15, lg = lane >> 4;
  const bf16* a0p = xb + (row0 + lr) * 512 + lg * 8;
  const bf16* a1p = a0p + 16 * 512;
  const bf16* b0p = Wt + (col0 + lr) * 512 + lg * 8;
  const bf16* b1p = b0p + 16 * 512;
  f32x4 acc00 = {0.f,0.f,0.f,0.f}, acc01 = acc00, acc10 = acc00, acc11 = acc00;
#pragma unroll
  for (int kk = 0; kk < 512; kk += 32) {
    bf16x8 a0 = *reinterpret_cast<const bf16x8*>(a0p + kk);
    bf16x8 a1 = *reinterpret_cast<const bf16x8*>(a1p + kk);
    bf16x8 b0 = *reinterpret_cast<const bf16x8*>(b0p + kk);
    bf16x8 b1 = *reinterpret_cast<const bf16x8*>(b1p + kk);
    acc00 = mfma_bf16(a0, b0, acc00);
    acc01 = mfma_bf16(a0, b1, acc01);
    acc10 = mfma_bf16(a1, b0, acc10);
    acc11 = mfma_bf16(a1, b1, acc11);
  }
#pragma unroll
  for (int ni = 0; ni < 2; ++ni) {
    int col = col0 + ni * 16 + lr;
    int wsel = col >> 9;
    int ncol = col & 511;
    int h = ncol >> 6, d = ncol & 63;
    const float* bias = wsel == 0 ? bq : (wsel == 1 ? bk : bv);
    float bval = bias[ncol];
#pragma unroll
    for (int mi = 0; mi < 2; ++mi) {
      f32x4 acc = (mi == 0) ? (ni == 0 ? acc00 : acc01) : (ni == 0 ? acc10 : acc11);
      int m0 = row0 + mi * 16 + lg * 4;
      int bidx = m0 >> 10, l0 = m0 & 1023;
      if (wsel == 2) {
        bf16x4 pv;
#pragma unroll
        for (int r = 0; r < 4; ++r) pv[r] = (bf16)(acc[r] + bval);
        *reinterpret_cast<bf16x4*>(vT + ((long)(bidx * H_ + h) * D_ + d) * L_ + l0) = pv;
      } else if (wsel == 0) {
#pragma unroll
        for (int r = 0; r < 4; ++r)
          qb[((long)(bidx * H_ + h) * L_ + l0 + r) * D_ + d] = (bf16)((acc[r] + bval) * 0.125f);
      } else {
#pragma unroll
        for (int r = 0; r < 4; ++r)
          kb[((long)(bidx * H_ + h) * L_ + l0 + r) * D_ + d] = (bf16)(acc[r] + bval);
      }
    }
  }
}

// ---------------- bias: z(2M x 64) @ Wtpb^T -> bias fp16 [b][h][i][j] ----------------
__global__ __launch_bounds__(256) void bias_gemm(
    const float* __restrict__ z, const bf16* __restrict__ Wtpb, _Float16* __restrict__ biasbuf) {
  __shared__ float zt_raw[64 * 64];   // 16KB: 64 pairs x 256B, col ^= (row&7)<<5
  __shared__ _Float16 bt[8][72];
  int tid = threadIdx.x;
  int w = tid >> 6, lane = tid & 63;
  int lr = lane & 15, lg = lane >> 4;
  char* zb = (char*)zt_raw;
  const char* zsrc = (const char*)(z + (long)blockIdx.x * 4096);  // 64 pairs * 64 f32
#pragma unroll
  for (int q = 0; q < 4; ++q) {
    int lb = q * 4096 + tid * 16;
    int row = lb >> 8, col = lb & 255;
    f32x4 v = *reinterpret_cast<const f32x4*>(zsrc + lb);
    *reinterpret_cast<f32x4*>(zb + row * 256 + (col ^ ((row & 7) << 5))) = v;
  }
  bf16x8 b0 = *reinterpret_cast<const bf16x8*>(Wtpb + lr * 64 + lg * 8);
  bf16x8 b1 = *reinterpret_cast<const bf16x8*>(Wtpb + lr * 64 + 32 + lg * 8);
  __syncthreads();
  int row = w * 16 + lr;
  int sw = (row & 7) << 5;
  const char* zr = zb + row * 256;
  f32x4 z0 = *reinterpret_cast<const f32x4*>(zr + ((lg * 32) ^ sw));
  f32x4 z1 = *reinterpret_cast<const f32x4*>(zr + (((lg * 32) ^ sw) + 16));
  f32x4 z2 = *reinterpret_cast<const f32x4*>(zr + ((128 + lg * 32) ^ sw));
  f32x4 z3 = *reinterpret_cast<const f32x4*>(zr + (((128 + lg * 32) ^ sw) + 16));
  bf16x8 a0, a1;
#pragma unroll
  for (int e = 0; e < 4; ++e) { a0[e] = (bf16)z0[e]; a0[e + 4] = (bf16)z1[e]; }
#pragma unroll
  for (int e = 0; e < 4; ++e) { a1[e] = (bf16)z2[e]; a1[e + 4] = (bf16)z3[e]; }
  f32x4 acc = {0.f, 0.f, 0.f, 0.f};
  acc = mfma_bf16(a0, b0, acc);
  acc = mfma_bf16(a1, b1, acc);
  __syncthreads();
  if (lr < 8) {                        // h = lr, j-local = w*16 + lg*4 + r
    f16x4 hv;
#pragma unroll
    for (int r = 0; r < 4; ++r) hv[r] = (_Float16)acc[r];
    *reinterpret_cast<f16x4*>(&bt[lr][w * 16 + lg * 4]) = hv;
  }
  __syncthreads();
  {
    int h = tid >> 5, part = tid & 31;
    long pb = (long)blockIdx.x * 64;
    int b = (int)(pb >> 20), i = ((int)(pb >> 10)) & 1023, j0 = (int)pb & 1023;
    _Float16* dst = biasbuf + ((((long)b * H_ + h) * L_ + i) << 10) + j0 + part * 2;
    *reinterpret_cast<f16x2*>(dst) = *reinterpret_cast<const f16x2*>(&bt[h][part * 2]);
  }
}

// ---------------- attention: MFMA flash (REP_ATTN idempotent reps for measurement) ----------------
__global__ __launch_bounds__(256) void attn_kernel(
    const bf16* __restrict__ qb, const bf16* __restrict__ kb, const bf16* __restrict__ vT,
    const _Float16* __restrict__ biasbuf, const int* __restrict__ mask, bf16* __restrict__ attn_out) {
  __shared__ bf16  p_lds[4][16][64];   // XOR-swizzled (byte ^= (row&7)<<4), 128B row stride
  __shared__ float o_lds[4][16][64];
  __shared__ float m_lds[4][16];
  __shared__ float l_lds[4][16];
  int bid = blockIdx.x;
  int b = bid >> 9, h = (bid >> 6) & 7, it = bid & 63;
  int i0 = it * 16;
  int tid = threadIdx.x, w = tid >> 6, lane = tid & 63, lr = lane & 15, lg = lane >> 4;

  const bf16* qrow = qb + ((long)(b * H_ + h) * L_ + i0 + lr) * D_ + lg * 8;
  bf16x8 qa0 = *reinterpret_cast<const bf16x8*>(qrow);
  bf16x8 qa1 = *reinterpret_cast<const bf16x8*>(qrow + 32);
  const bf16* kbase = kb + (long)(b * H_ + h) * L_ * D_;
  const bf16* vbase = vT + (long)(b * H_ + h) * D_ * L_;
  const _Float16* bias_base = biasbuf + ((long)(b * H_ + h) * L_ + i0) * L_;
  const int* mrow_mask = mask + b * L_;

  bool qok[4];
#pragma unroll
  for (int r = 0; r < 4; ++r) qok[r] = mrow_mask[i0 + lg * 4 + r] != 0;

  for (int rep = 0; rep < REP_ATTN; ++rep) {
    asm volatile("" ::: "memory");
    float mr[4] = {-3.0e38f, -3.0e38f, -3.0e38f, -3.0e38f};
    float lsum[4] = {0.f, 0.f, 0.f, 0.f};
    f32x4 o0 = {0.f,0.f,0.f,0.f}, o1 = o0, o2 = o0, o3 = o0;

    char* p_base = (char*)&p_lds[w][0][0];

    for (int jt = 0; jt < 4; ++jt) {
      int j0 = w * 256 + jt * 64;
      f32x4 s0, s1, s2, s3;
#pragma unroll
      for (int jsub = 0; jsub < 4; ++jsub) {
        int j = j0 + jsub * 16 + lr;
        f32x4 acc;
#pragma unroll
        for (int r = 0; r < 4; ++r) acc[r] = (float)bias_base[(long)(lg * 4 + r) * L_ + j];
        const bf16* kr = kbase + (long)j * D_ + lg * 8;
        acc = mfma_bf16(qa0, *reinterpret_cast<const bf16x8*>(kr), acc);
        acc = mfma_bf16(qa1, *reinterpret_cast<const bf16x8*>(kr + 32), acc);
        bool kok = mrow_mask[j] != 0;
        if (!kok) {
#pragma unroll
          for (int r = 0; r < 4; ++r) acc[r] = NEG_VAL;
        }
        if (jsub == 0) s0 = acc; else if (jsub == 1) s1 = acc; else if (jsub == 2) s2 = acc; else s3 = acc;
      }
#pragma unroll
      for (int r = 0; r < 4; ++r) {
        if (!qok[r]) { s0[r] = NEG_VAL; s1[r] = NEG_VAL; s2[r] = NEG_VAL; s3[r] = NEG_VAL; }
      }
#pragma unroll
      for (int r = 0; r < 4; ++r) {
        float mt_ = fmaxf(fmaxf(s0[r], s1[r]), fmaxf(s2[r], s3[r]));
#pragma unroll
        for (int off = 1; off <= 8; off <<= 1) mt_ = fmaxf(mt_, __shfl_xor(mt_, off));
        float mnew = fmaxf(mr[r], mt_);
        float alpha = __expf(mr[r] - mnew);
        mr[r] = mnew;
        float p0 = __expf(s0[r] - mnew);
        float p1 = __expf(s1[r] - mnew);
        float p2 = __expf(s2[r] - mnew);
        float p3 = __expf(s3[r] - mnew);
        float ps = p0 + p1 + p2 + p3;
#pragma unroll
        for (int off = 1; off <= 8; off <<= 1) ps += __shfl_xor(ps, off);
        lsum[r] = lsum[r] * alpha + ps;
        o0[r] *= alpha; o1[r] *= alpha; o2[r] *= alpha; o3[r] *= alpha;
        int row = lg * 4 + r;
        int sw = (row & 7) << 4;
        *(bf16*)(p_base + row * 128 + ((lr * 2) ^ sw)) = (bf16)p0;
        *(bf16*)(p_base + row * 128 + ((32 + lr * 2) ^ sw)) = (bf16)p1;
        *(bf16*)(p_base + row * 128 + ((64 + lr * 2) ^ sw)) = (bf16)p2;
        *(bf16*)(p_base + row * 128 + ((96 + lr * 2) ^ sw)) = (bf16)p3;
      }
      int swr = (lr & 7) << 4;
      bf16x8 pa0 = *(const bf16x8*)(p_base + lr * 128 + ((lg * 16) ^ swr));
      bf16x8 pa1 = *(const bf16x8*)(p_base + lr * 128 + ((64 + lg * 16) ^ swr));
#pragma unroll
      for (int dsub = 0; dsub < 4; ++dsub) {
        const bf16* vr = vbase + (long)(dsub * 16 + lr) * L_ + j0 + lg * 8;
        bf16x8 vb0 = *reinterpret_cast<const bf16x8*>(vr);
        bf16x8 vb1 = *reinterpret_cast<const bf16x8*>(vr + 32);
        f32x4 acc = (dsub == 0) ? o0 : (dsub == 1) ? o1 : (dsub == 2) ? o2 : o3;
        acc = mfma_bf16(pa0, vb0, acc);
        acc = mfma_bf16(pa1, vb1, acc);
        if (dsub == 0) o0 = acc; else if (dsub == 1) o1 = acc; else if (dsub == 2) o2 = acc; else o3 = acc;
      }
    }
#pragma unroll
    for (int r = 0; r < 4; ++r) {
      int row = lg * 4 + r;
      o_lds[w][row][0 * 16 + lr] = o0[r];
      o_lds[w][row][1 * 16 + lr] = o1[r];
      o_lds[w][row][2 * 16 + lr] = o2[r];
      o_lds[w][row][3 * 16 + lr] = o3[r];
      if (lr == 0) { m_lds[w][row] = mr[r]; l_lds[w][row] = lsum[r]; }
    }
    __syncthreads();
    {
      int row = tid >> 4, d0 = (tid & 15) * 4;
      float M = fmaxf(fmaxf(m_lds[0][row], m_lds[1][row]), fmaxf(m_lds[2][row], m_lds[3][row]));
      float lt = 0.f;
      float oacc[4] = {0.f, 0.f, 0.f, 0.f};
#pragma unroll
      for (int ww = 0; ww < 4; ++ww) {
        float c = __expf(m_lds[ww][row] - M);
        lt += c * l_lds[ww][row];
#pragma unroll
        for (int e = 0; e < 4; ++e) oacc[e] += c * o_lds[ww][row][d0 + e];
      }
      float inv = 1.0f / lt;
      bf16x4 ov;
#pragma unroll
      for (int e = 0; e < 4; ++e) ov[e] = (bf16)(oacc[e] * inv);
      *reinterpret_cast<bf16x4*>(attn_out + ((long)(b * L_ + i0 + row)) * DM_ + h * D_ + d0) = ov;
    }
    __syncthreads();   // protect o_lds/m_lds/l_lds WAR across reps
  }
}

// ---------------- out: attn_out(2048x512) @ Wto^T -> d_out fp32 + bo (REP_OUT reps) ----------------
__global__ __launch_bounds__(256) void out_gemm(
    const bf16* __restrict__ ab, const bf16* __restrict__ Wto,
    const float* __restrict__ bo, float* __restrict__ out) {
  int wid = blockIdx.x * 4 + (threadIdx.x >> 6);
  int lane = threadIdx.x & 63;
  int mt = wid >> 4, nt = wid & 15;    // 64 x 16 tiles of 32x32
  int row0 = mt * 32, col0 = nt * 32;
  int lr = lane & 15, lg = lane >> 4;
  const bf16* a0p = ab + (row0 + lr) * 512 + lg * 8;
  const bf16* a1p = a0p + 16 * 512;
  const bf16* b0p = Wto + (col0 + lr) * 512 + lg * 8;
  const bf16* b1p = b0p + 16 * 512;
  for (int rep = 0; rep < REP_OUT; ++rep) {
    asm volatile("" ::: "memory");
    f32x4 acc00 = {0.f,0.f,0.f,0.f}, acc01 = acc00, acc10 = acc00, acc11 = acc00;
#pragma unroll
    for (int kk = 0; kk < 512; kk += 32) {
      bf16x8 a0 = *reinterpret_cast<const bf16x8*>(a0p + kk);
      bf16x8 a1 = *reinterpret_cast<const bf16x8*>(a1p + kk);
      bf16x8 b0 = *reinterpret_cast<const bf16x8*>(b0p + kk);
      bf16x8 b1 = *reinterpret_cast<const bf16x8*>(b1p + kk);
      acc00 = mfma_bf16(a0, b0, acc00);
      acc01 = mfma_bf16(a0, b1, acc01);
      acc10 = mfma_bf16(a1, b0, acc10);
      acc11 = mfma_bf16(a1, b1, acc11);
    }
#pragma unroll
    for (int ni = 0; ni < 2; ++ni) {
      int col = col0 + ni * 16 + lr;
      float bval = bo[col];
#pragma unroll
      for (int mi = 0; mi < 2; ++mi) {
        f32x4 acc = (mi == 0) ? (ni == 0 ? acc00 : acc01) : (ni == 0 ? acc10 : acc11);
        int m0 = row0 + mi * 16 + lg * 4;
#pragma unroll
        for (int r = 0; r < 4; ++r) out[(long)(m0 + r) * 512 + col] = acc[r] + bval;
      }
    }
  }
}

extern "C" void kernel_launch(void* const* d_in, const int* in_sizes, int n_in,
                              void* d_out, int out_size, void* d_ws, size_t ws_size,
                              hipStream_t stream) {
  const float* x    = (const float*)d_in[0];
  const float* z    = (const float*)d_in[1];
  const int*   mask = (const int*)d_in[2];
  const float* Wq   = (const float*)d_in[3];
  const float* bq   = (const float*)d_in[4];
  const float* Wk   = (const float*)d_in[5];
  const float* bk   = (const float*)d_in[6];
  const float* Wv   = (const float*)d_in[7];
  const float* bv   = (const float*)d_in[8];
  const float* Wo   = (const float*)d_in[9];
  const float* bo   = (const float*)d_in[10];
  const float* Wpb  = (const float*)d_in[11];

  char* ws = (char*)d_ws;
  bf16* xb        = (bf16*)(ws + 0);                    // 2 MB
  bf16* Wt        = (bf16*)(ws + 2097152);              // 1.5 MB
  bf16* Wto       = (bf16*)(ws + 3670016);              // 0.5 MB
  bf16* Wtpb      = (bf16*)(ws + 4194304);              // 2 KB
  bf16* qbuf      = (bf16*)(ws + 4196352);              // 2 MB
  bf16* kbuf      = (bf16*)(ws + 6293504);              // 2 MB
  bf16* vTbuf     = (bf16*)(ws + 8390656);              // 2 MB
  bf16* attn_out  = (bf16*)(ws + 10487808);             // 2 MB
  _Float16* biasb = (_Float16*)(ws + 12584960);         // 33.5 MB

  prep_kernel<<<2048, 256, 0, stream>>>(x, Wq, Wk, Wv, Wo, Wpb, xb, Wt, Wto, Wtpb);
  qkv_gemm<<<768, 256, 0, stream>>>(xb, Wt, bq, bk, bv, qbuf, kbuf, vTbuf);
  bias_gemm<<<32768, 256, 0, stream>>>(z, Wtpb, biasb);
  attn_kernel<<<1024, 256, 0, stream>>>(qbuf, kbuf, vTbuf, biasb, mask, attn_out);
  out_gemm<<<256, 256, 0, stream>>>(attn_out, Wto, bo, (float*)d_out);
}

// Round 9
// 202.202 us; speedup vs baseline: 16.3567x; 16.3567x over previous
//
#include <hip/hip_runtime.h>

typedef __bf16 bf16;
typedef __attribute__((ext_vector_type(4))) __bf16 bf16x4;
typedef __attribute__((ext_vector_type(8))) __bf16 bf16x8;
typedef __attribute__((ext_vector_type(4))) float f32x4;
typedef __attribute__((ext_vector_type(4))) _Float16 f16x4;
typedef __attribute__((ext_vector_type(2))) _Float16 f16x2;

#define B_   2
#define L_   1024
#define DM_  512
#define H_   8
#define D_   64
#define PD_  64
#define NEG_VAL -10000.0f

#define XB_N   (2048*512)
#define WT_N   (1536*512)
#define WTO_N  (512*512)
#define WTPB_N (16*64)

static __device__ __forceinline__ f32x4 mfma_bf16(bf16x8 a, bf16x8 b, f32x4 c) {
  return __builtin_amdgcn_mfma_f32_16x16x32_bf16(a, b, c, 0, 0, 0);
}

// ---------------- prep: convert & transpose weights, convert x ----------------
__global__ __launch_bounds__(256) void prep_kernel(
    const float* __restrict__ x, const float* __restrict__ Wq, const float* __restrict__ Wk,
    const float* __restrict__ Wv, const float* __restrict__ Wo, const float* __restrict__ Wpb,
    bf16* __restrict__ xb, bf16* __restrict__ Wt, bf16* __restrict__ Wto, bf16* __restrict__ Wtpb) {
  const int total = XB_N + WT_N + WTO_N + WTPB_N;
  for (int idx = blockIdx.x * 256 + threadIdx.x; idx < total; idx += gridDim.x * 256) {
    if (idx < XB_N) {
      xb[idx] = (bf16)x[idx];
    } else if (idx < XB_N + WT_N) {
      int t = idx - XB_N;
      int n = t >> 9, kk = t & 511;       // Wt[n][k]
      int sel = n >> 9, nn = n & 511;
      const float* W = sel == 0 ? Wq : (sel == 1 ? Wk : Wv);
      Wt[t] = (bf16)W[kk * 512 + nn];
    } else if (idx < XB_N + WT_N + WTO_N) {
      int t = idx - XB_N - WT_N;
      int n = t >> 9, kk = t & 511;
      Wto[t] = (bf16)Wo[kk * 512 + n];
    } else {
      int t = idx - XB_N - WT_N - WTO_N;
      int n = t >> 6, kk = t & 63;
      Wtpb[t] = (n < 8) ? (bf16)Wpb[kk * 8 + n] : (bf16)0.0f;
    }
  }
}

// ---------------- qkv: xb(2048x512) @ Wt^T -> q,k bf16 [b][h][l][d], vT bf16 [b][h][d][l] ----------------
__global__ __launch_bounds__(256) void qkv_gemm(
    const bf16* __restrict__ xb, const bf16* __restrict__ Wt,
    const float* __restrict__ bq, const float* __restrict__ bk, const float* __restrict__ bv,
    bf16* __restrict__ qb, bf16* __restrict__ kb, bf16* __restrict__ vT) {
  int wid = blockIdx.x * 4 + (threadIdx.x >> 6);
  int lane = threadIdx.x & 63;
  int mt = wid / 48, nt = wid - mt * 48;   // 64 x 48 tiles of 32x32
  int row0 = mt * 32, col0 = nt * 32;
  int lr = lane & 15, lg = lane >> 4;
  const bf16* a0p = xb + (row0 + lr) * 512 + lg * 8;
  const bf16* a1p = a0p + 16 * 512;
  const bf16* b0p = Wt + (col0 + lr) * 512 + lg * 8;
  const bf16* b1p = b0p + 16 * 512;
  f32x4 acc00 = {0.f,0.f,0.f,0.f}, acc01 = acc00, acc10 = acc00, acc11 = acc00;
#pragma unroll
  for (int kk = 0; kk < 512; kk += 32) {
    bf16x8 a0 = *reinterpret_cast<const bf16x8*>(a0p + kk);
    bf16x8 a1 = *reinterpret_cast<const bf16x8*>(a1p + kk);
    bf16x8 b0 = *reinterpret_cast<const bf16x8*>(b0p + kk);
    bf16x8 b1 = *reinterpret_cast<const bf16x8*>(b1p + kk);
    acc00 = mfma_bf16(a0, b0, acc00);
    acc01 = mfma_bf16(a0, b1, acc01);
    acc10 = mfma_bf16(a1, b0, acc10);
    acc11 = mfma_bf16(a1, b1, acc11);
  }
#pragma unroll
  for (int ni = 0; ni < 2; ++ni) {
    int col = col0 + ni * 16 + lr;
    int wsel = col >> 9;
    int ncol = col & 511;
    int h = ncol >> 6, d = ncol & 63;
    const float* bias = wsel == 0 ? bq : (wsel == 1 ? bk : bv);
    float bval = bias[ncol];
#pragma unroll
    for (int mi = 0; mi < 2; ++mi) {
      f32x4 acc = (mi == 0) ? (ni == 0 ? acc00 : acc01) : (ni == 0 ? acc10 : acc11);
      int m0 = row0 + mi * 16 + lg * 4;
      int bidx = m0 >> 10, l0 = m0 & 1023;
      if (wsel == 2) {
        bf16x4 pv;
#pragma unroll
        for (int r = 0; r < 4; ++r) pv[r] = (bf16)(acc[r] + bval);
        *reinterpret_cast<bf16x4*>(vT + ((long)(bidx * H_ + h) * D_ + d) * L_ + l0) = pv;
      } else if (wsel == 0) {
#pragma unroll
        for (int r = 0; r < 4; ++r)
          qb[((long)(bidx * H_ + h) * L_ + l0 + r) * D_ + d] = (bf16)((acc[r] + bval) * 0.125f);
      } else {
#pragma unroll
        for (int r = 0; r < 4; ++r)
          kb[((long)(bidx * H_ + h) * L_ + l0 + r) * D_ + d] = (bf16)(acc[r] + bval);
      }
    }
  }
}

// ---------------- bias: z @ Wtpb^T -> bias fp16 [b][h][i][j], key-mask folded in ----------------
__global__ __launch_bounds__(256) void bias_gemm(
    const float* __restrict__ z, const bf16* __restrict__ Wtpb, const int* __restrict__ mask,
    _Float16* __restrict__ biasbuf) {
  __shared__ float zt_raw[64 * 64];   // 16KB: 64 pairs x 256B, col ^= (row&7)<<5
  __shared__ _Float16 bt[8][72];
  int tid = threadIdx.x;
  int w = tid >> 6, lane = tid & 63;
  int lr = lane & 15, lg = lane >> 4;
  char* zb = (char*)zt_raw;
  const char* zsrc = (const char*)(z + (long)blockIdx.x * 4096);  // 64 pairs * 64 f32
#pragma unroll
  for (int q = 0; q < 4; ++q) {
    int lb = q * 4096 + tid * 16;
    int row = lb >> 8, col = lb & 255;
    f32x4 v = *reinterpret_cast<const f32x4*>(zsrc + lb);
    *reinterpret_cast<f32x4*>(zb + row * 256 + (col ^ ((row & 7) << 5))) = v;
  }
  bf16x8 b0 = *reinterpret_cast<const bf16x8*>(Wtpb + lr * 64 + lg * 8);
  bf16x8 b1 = *reinterpret_cast<const bf16x8*>(Wtpb + lr * 64 + 32 + lg * 8);
  __syncthreads();
  int row = w * 16 + lr;
  int sw = (row & 7) << 5;
  const char* zr = zb + row * 256;
  f32x4 z0 = *reinterpret_cast<const f32x4*>(zr + ((lg * 32) ^ sw));
  f32x4 z1 = *reinterpret_cast<const f32x4*>(zr + (((lg * 32) ^ sw) + 16));
  f32x4 z2 = *reinterpret_cast<const f32x4*>(zr + ((128 + lg * 32) ^ sw));
  f32x4 z3 = *reinterpret_cast<const f32x4*>(zr + (((128 + lg * 32) ^ sw) + 16));
  bf16x8 a0, a1;
#pragma unroll
  for (int e = 0; e < 4; ++e) { a0[e] = (bf16)z0[e]; a0[e + 4] = (bf16)z1[e]; }
#pragma unroll
  for (int e = 0; e < 4; ++e) { a1[e] = (bf16)z2[e]; a1[e + 4] = (bf16)z3[e]; }
  f32x4 acc = {0.f, 0.f, 0.f, 0.f};
  acc = mfma_bf16(a0, b0, acc);
  acc = mfma_bf16(a1, b1, acc);
  __syncthreads();
  if (lr < 8) {                        // h = lr, j-local = w*16 + lg*4 + r
    f16x4 hv;
#pragma unroll
    for (int r = 0; r < 4; ++r) hv[r] = (_Float16)acc[r];
    *reinterpret_cast<f16x4*>(&bt[lr][w * 16 + lg * 4]) = hv;
  }
  __syncthreads();
  {
    int h = tid >> 5, part = tid & 31;
    long pb = (long)blockIdx.x * 64;
    int b = (int)(pb >> 20), i = ((int)(pb >> 10)) & 1023, j0 = (int)pb & 1023;
    int j = j0 + part * 2;
    f16x2 v = *reinterpret_cast<const f16x2*>(&bt[h][part * 2]);
    if (mask[b * L_ + j] == 0)     v[0] = (_Float16)NEG_VAL;   // fold key_ok into bias
    if (mask[b * L_ + j + 1] == 0) v[1] = (_Float16)NEG_VAL;
    _Float16* dst = biasbuf + ((((long)b * H_ + h) * L_ + i) << 10) + j;
    *reinterpret_cast<f16x2*>(dst) = v;
  }
}

// ---------------- attention partials: swapped-operand MFMA flash ----------------
// grid: bid -> jc=bid&1, it=(bid>>1)&63, h=(bid>>7)&7, b=bid>>10. 4 waves, wave w
// covers j = jc*512 + w*128 (2 j-tiles of 64). S fragment: col=i (lane&15), row=j.
// No barriers, no cross-wave merge: each wave writes its own (m,l,o) partial.
__global__ __launch_bounds__(256) void attn_part(
    const bf16* __restrict__ qb, const bf16* __restrict__ kb, const bf16* __restrict__ vT,
    const _Float16* __restrict__ biasb, const int* __restrict__ mask,
    float* __restrict__ part_o, float* __restrict__ part_m, float* __restrict__ part_l) {
  __shared__ bf16 p_lds[4][16 * 64];   // per wave: 16 i-rows x 64 j, XOR-swizzled rows of 128B
  int bid = blockIdx.x;
  int jc = bid & 1, it = (bid >> 1) & 63, h = (bid >> 7) & 7, b = bid >> 10;
  int i0 = it * 16;
  int tid = threadIdx.x, w = tid >> 6, lane = tid & 63, lr = lane & 15, lg = lane >> 4;

  const bf16* qrow = qb + ((long)(b * H_ + h) * L_ + i0 + lr) * D_ + lg * 8;
  bf16x8 qa0 = *reinterpret_cast<const bf16x8*>(qrow);        // B-frag: col=i, k=d
  bf16x8 qa1 = *reinterpret_cast<const bf16x8*>(qrow + 32);
  const bf16* kbase = kb + (long)(b * H_ + h) * L_ * D_;
  const bf16* vbase = vT + (long)(b * H_ + h) * D_ * L_;
  const _Float16* bias_base = biasb + ((long)(b * H_ + h) * L_ + i0) * L_;
  bool qok = mask[b * L_ + i0 + lr] != 0;

  float m = -3.0e38f, l = 0.f;
  f32x4 o0 = {0.f,0.f,0.f,0.f}, o1 = o0, o2 = o0, o3 = o0;   // o[dtile][r]: d=dtile*16+lg*4+r, i=lr
  char* pbuf = (char*)&p_lds[w][0];
  int swz = (lr & 7) << 4;
  int jbase = jc * 512 + w * 128;

  for (int jt = 0; jt < 2; ++jt) {
    int j0 = jbase + jt * 64;
    f32x4 s0, s1, s2, s3;
#pragma unroll
    for (int tile = 0; tile < 4; ++tile) {
      // bias init: contiguous f16x4 per lane (i=lr row, 4 consecutive j)
      f16x4 bv = *reinterpret_cast<const f16x4*>(bias_base + (long)lr * L_ + j0 + tile * 16 + lg * 4);
      f32x4 acc;
#pragma unroll
      for (int r = 0; r < 4; ++r) acc[r] = (float)bv[r];
      const bf16* kr = kbase + (long)(j0 + tile * 16 + lr) * D_ + lg * 8;   // A-frag: row=j, k=d
      acc = mfma_bf16(*reinterpret_cast<const bf16x8*>(kr), qa0, acc);
      acc = mfma_bf16(*reinterpret_cast<const bf16x8*>(kr + 32), qa1, acc);
      if (tile == 0) s0 = acc; else if (tile == 1) s1 = acc; else if (tile == 2) s2 = acc; else s3 = acc;
    }
    if (!qok) {
#pragma unroll
      for (int r = 0; r < 4; ++r) { s0[r] = NEG_VAL; s1[r] = NEG_VAL; s2[r] = NEG_VAL; s3[r] = NEG_VAL; }
    }
    // softmax over row i=lr: 16 in-lane values + lanes differing in bits 4,5 (lg)
    float mt = s0[0];
#pragma unroll
    for (int r = 0; r < 4; ++r) mt = fmaxf(fmaxf(fmaxf(mt, s0[r]), fmaxf(s1[r], s2[r])), s3[r]);
    mt = fmaxf(mt, __shfl_xor(mt, 16));
    mt = fmaxf(mt, __shfl_xor(mt, 32));
    float mnew = fmaxf(m, mt);
    float alpha = __expf(m - mnew);
    m = mnew;
    f32x4 p0, p1, p2, p3;
    float ps = 0.f;
#pragma unroll
    for (int r = 0; r < 4; ++r) {
      p0[r] = __expf(s0[r] - mnew); p1[r] = __expf(s1[r] - mnew);
      p2[r] = __expf(s2[r] - mnew); p3[r] = __expf(s3[r] - mnew);
      ps += p0[r] + p1[r] + p2[r] + p3[r];
    }
    ps += __shfl_xor(ps, 16);
    ps += __shfl_xor(ps, 32);
    l = l * alpha + ps;
#pragma unroll
    for (int r = 0; r < 4; ++r) { o0[r] *= alpha; o1[r] *= alpha; o2[r] *= alpha; o3[r] *= alpha; }
    // P -> LDS: lane holds P[i=lr][j0loc = tile*16 + lg*4 .. +3], write f16x4 (8B)
#pragma unroll
    for (int tile = 0; tile < 4; ++tile) {
      f32x4 pv = (tile == 0) ? p0 : (tile == 1) ? p1 : (tile == 2) ? p2 : p3;
      bf16x4 pb_;
#pragma unroll
      for (int r = 0; r < 4; ++r) pb_[r] = (bf16)pv[r];
      *reinterpret_cast<bf16x4*>(pbuf + ((lr * 128 + tile * 32 + lg * 8) ^ swz)) = pb_;
    }
    // PV: B-frag pa: lane holds P[i=lr][k-slice lg*8], per 32-j block
    bf16x8 pa0 = *reinterpret_cast<const bf16x8*>(pbuf + ((lr * 128 + lg * 16) ^ swz));
    bf16x8 pa1 = *reinterpret_cast<const bf16x8*>(pbuf + ((lr * 128 + 64 + lg * 16) ^ swz));
#pragma unroll
    for (int dtile = 0; dtile < 4; ++dtile) {
      const bf16* vr = vbase + (long)(dtile * 16 + lr) * L_ + j0 + lg * 8;   // A-frag: row=d, k=j
      f32x4 acc = (dtile == 0) ? o0 : (dtile == 1) ? o1 : (dtile == 2) ? o2 : o3;
      acc = mfma_bf16(*reinterpret_cast<const bf16x8*>(vr), pa0, acc);
      acc = mfma_bf16(*reinterpret_cast<const bf16x8*>(vr + 32), pa1, acc);
      if (dtile == 0) o0 = acc; else if (dtile == 1) o1 = acc; else if (dtile == 2) o2 = acc; else o3 = acc;
    }
  }
  // write per-wave partial: [wid][i(16)][d(64)] f32 + m,l
  int wid = bid * 4 + w;
  float* po = part_o + (long)wid * 1024;
#pragma unroll
  for (int dtile = 0; dtile < 4; ++dtile) {
    f32x4 ov = (dtile == 0) ? o0 : (dtile == 1) ? o1 : (dtile == 2) ? o2 : o3;
    *reinterpret_cast<f32x4*>(po + lr * 64 + dtile * 16 + lg * 4) = ov;
  }
  if (lg == 0) { part_m[wid * 16 + lr] = m; part_l[wid * 16 + lr] = l; }
}

// ---------------- merge8: combine 8 wave-partials -> attn_out bf16 ----------------
__global__ __launch_bounds__(256) void merge8(
    const float* __restrict__ part_o, const float* __restrict__ part_m,
    const float* __restrict__ part_l, bf16* __restrict__ attn_out) {
  int t = blockIdx.x * 256 + threadIdx.x;     // 262144 threads
  int d0 = (t & 15) * 4;
  int row = t >> 4;                            // (b,h,i)
  int b = row >> 13, h = (row >> 10) & 7, i = row & 1023;
  int it = i >> 4, il = i & 15;
  int bid0 = ((b * H_ + h) * 64 + it) * 2;
  float mv[8];
  float M = -3.0e38f;
#pragma unroll
  for (int p = 0; p < 8; ++p) {
    int wid = (bid0 + (p >> 2)) * 4 + (p & 3);
    mv[p] = part_m[wid * 16 + il];
    M = fmaxf(M, mv[p]);
  }
  float lt = 0.f;
  float oa[4] = {0.f, 0.f, 0.f, 0.f};
#pragma unroll
  for (int p = 0; p < 8; ++p) {
    int wid = (bid0 + (p >> 2)) * 4 + (p & 3);
    float c = __expf(mv[p] - M);
    lt += c * part_l[wid * 16 + il];
    f32x4 ov = *reinterpret_cast<const f32x4*>(part_o + ((long)wid * 16 + il) * 64 + d0);
#pragma unroll
    for (int e = 0; e < 4; ++e) oa[e] += c * ov[e];
  }
  float inv = 1.0f / lt;
  bf16x4 r_;
#pragma unroll
  for (int e = 0; e < 4; ++e) r_[e] = (bf16)(oa[e] * inv);
  *reinterpret_cast<bf16x4*>(attn_out + ((long)(b * L_ + i)) * DM_ + h * D_ + d0) = r_;
}

// ---------------- out: attn_out(2048x512) @ Wto^T -> d_out fp32 + bo ----------------
__global__ __launch_bounds__(256) void out_gemm(
    const bf16* __restrict__ ab, const bf16* __restrict__ Wto,
    const float* __restrict__ bo, float* __restrict__ out) {
  int wid = blockIdx.x * 4 + (threadIdx.x >> 6);
  int lane = threadIdx.x & 63;
  int mt = wid >> 4, nt = wid & 15;    // 64 x 16 tiles of 32x32
  int row0 = mt * 32, col0 = nt * 32;
  int lr = lane & 15, lg = lane >> 4;
  const bf16* a0p = ab + (row0 + lr) * 512 + lg * 8;
  const bf16* a1p = a0p + 16 * 512;
  const bf16* b0p = Wto + (col0 + lr) * 512 + lg * 8;
  const bf16* b1p = b0p + 16 * 512;
  f32x4 acc00 = {0.f,0.f,0.f,0.f}, acc01 = acc00, acc10 = acc00, acc11 = acc00;
#pragma unroll
  for (int kk = 0; kk < 512; kk += 32) {
    bf16x8 a0 = *reinterpret_cast<const bf16x8*>(a0p + kk);
    bf16x8 a1 = *reinterpret_cast<const bf16x8*>(a1p + kk);
    bf16x8 b0 = *reinterpret_cast<const bf16x8*>(b0p + kk);
    bf16x8 b1 = *reinterpret_cast<const bf16x8*>(b1p + kk);
    acc00 = mfma_bf16(a0, b0, acc00);
    acc01 = mfma_bf16(a0, b1, acc01);
    acc10 = mfma_bf16(a1, b0, acc10);
    acc11 = mfma_bf16(a1, b1, acc11);
  }
#pragma unroll
  for (int ni = 0; ni < 2; ++ni) {
    int col = col0 + ni * 16 + lr;
    float bval = bo[col];
#pragma unroll
    for (int mi = 0; mi < 2; ++mi) {
      f32x4 acc = (mi == 0) ? (ni == 0 ? acc00 : acc01) : (ni == 0 ? acc10 : acc11);
      int m0 = row0 + mi * 16 + lg * 4;
#pragma unroll
      for (int r = 0; r < 4; ++r) out[(long)(m0 + r) * 512 + col] = acc[r] + bval;
    }
  }
}

extern "C" void kernel_launch(void* const* d_in, const int* in_sizes, int n_in,
                              void* d_out, int out_size, void* d_ws, size_t ws_size,
                              hipStream_t stream) {
  const float* x    = (const float*)d_in[0];
  const float* z    = (const float*)d_in[1];
  const int*   mask = (const int*)d_in[2];
  const float* Wq   = (const float*)d_in[3];
  const float* bq   = (const float*)d_in[4];
  const float* Wk   = (const float*)d_in[5];
  const float* bk   = (const float*)d_in[6];
  const float* Wv   = (const float*)d_in[7];
  const float* bv   = (const float*)d_in[8];
  const float* Wo   = (const float*)d_in[9];
  const float* bo   = (const float*)d_in[10];
  const float* Wpb  = (const float*)d_in[11];

  char* ws = (char*)d_ws;
  bf16* xb        = (bf16*)(ws + 0);                    // 2 MB
  bf16* Wt        = (bf16*)(ws + 2097152);              // 1.5 MB
  bf16* Wto       = (bf16*)(ws + 3670016);              // 0.5 MB
  bf16* Wtpb      = (bf16*)(ws + 4194304);              // 2 KB
  bf16* qbuf      = (bf16*)(ws + 4196352);              // 2 MB
  bf16* kbuf      = (bf16*)(ws + 6293504);              // 2 MB
  bf16* vTbuf     = (bf16*)(ws + 8390656);              // 2 MB
  bf16* attn_out  = (bf16*)(ws + 10487808);             // 2 MB
  _Float16* biasb = (_Float16*)(ws + 12584960);         // 33.5 MB
  float* part_o   = (float*)(ws + 46139392);            // 33.5 MB (8192 waves x 16 x 64 f32)
  float* part_m   = (float*)(ws + 79693824);            // 512 KB
  float* part_l   = (float*)(ws + 80218112);            // 512 KB

  prep_kernel<<<2048, 256, 0, stream>>>(x, Wq, Wk, Wv, Wo, Wpb, xb, Wt, Wto, Wtpb);
  qkv_gemm<<<768, 256, 0, stream>>>(xb, Wt, bq, bk, bv, qbuf, kbuf, vTbuf);
  bias_gemm<<<32768, 256, 0, stream>>>(z, Wtpb, mask, biasb);
  attn_part<<<2048, 256, 0, stream>>>(qbuf, kbuf, vTbuf, biasb, mask, part_o, part_m, part_l);
  merge8<<<1024, 256, 0, stream>>>(part_o, part_m, part_l, attn_out);
  out_gemm<<<256, 256, 0, stream>>>(attn_out, Wto, bo, (float*)d_out);
}

// Round 10
// 188.481 us; speedup vs baseline: 17.5474x; 1.0728x over previous
//
#include <hip/hip_runtime.h>

typedef __bf16 bf16;
typedef __attribute__((ext_vector_type(4))) __bf16 bf16x4;
typedef __attribute__((ext_vector_type(8))) __bf16 bf16x8;
typedef __attribute__((ext_vector_type(4))) float f32x4;
typedef __attribute__((ext_vector_type(4))) _Float16 f16x4;
typedef __attribute__((ext_vector_type(2))) _Float16 f16x2;

#define B_   2
#define L_   1024
#define DM_  512
#define H_   8
#define D_   64
#define PD_  64
#define NEG_VAL -10000.0f

#define XB_N   (2048*512)
#define WT_N   (1536*512)
#define WTO_N  (512*512)
#define WTPB_N (16*64)

static __device__ __forceinline__ f32x4 mfma_bf16(bf16x8 a, bf16x8 b, f32x4 c) {
  return __builtin_amdgcn_mfma_f32_16x16x32_bf16(a, b, c, 0, 0, 0);
}

// ---------------- prep: convert & transpose weights, convert x ----------------
__global__ __launch_bounds__(256) void prep_kernel(
    const float* __restrict__ x, const float* __restrict__ Wq, const float* __restrict__ Wk,
    const float* __restrict__ Wv, const float* __restrict__ Wo, const float* __restrict__ Wpb,
    bf16* __restrict__ xb, bf16* __restrict__ Wt, bf16* __restrict__ Wto, bf16* __restrict__ Wtpb) {
  const int total = XB_N + WT_N + WTO_N + WTPB_N;
  for (int idx = blockIdx.x * 256 + threadIdx.x; idx < total; idx += gridDim.x * 256) {
    if (idx < XB_N) {
      xb[idx] = (bf16)x[idx];
    } else if (idx < XB_N + WT_N) {
      int t = idx - XB_N;
      int n = t >> 9, kk = t & 511;       // Wt[n][k]
      int sel = n >> 9, nn = n & 511;
      const float* W = sel == 0 ? Wq : (sel == 1 ? Wk : Wv);
      Wt[t] = (bf16)W[kk * 512 + nn];
    } else if (idx < XB_N + WT_N + WTO_N) {
      int t = idx - XB_N - WT_N;
      int n = t >> 9, kk = t & 511;
      Wto[t] = (bf16)Wo[kk * 512 + n];
    } else {
      int t = idx - XB_N - WT_N - WTO_N;
      int n = t >> 6, kk = t & 63;
      Wtpb[t] = (n < 8) ? (bf16)Wpb[kk * 8 + n] : (bf16)0.0f;
    }
  }
}

// ---------------- qkv: xb(2048x512) @ Wt^T -> q,k bf16 [b][h][l][d], vT bf16 [b][h][d][l] ----------------
__global__ __launch_bounds__(256) void qkv_gemm(
    const bf16* __restrict__ xb, const bf16* __restrict__ Wt,
    const float* __restrict__ bq, const float* __restrict__ bk, const float* __restrict__ bv,
    bf16* __restrict__ qb, bf16* __restrict__ kb, bf16* __restrict__ vT) {
  int wid = blockIdx.x * 4 + (threadIdx.x >> 6);
  int lane = threadIdx.x & 63;
  int mt = wid / 48, nt = wid - mt * 48;   // 64 x 48 tiles of 32x32
  int row0 = mt * 32, col0 = nt * 32;
  int lr = lane & 15, lg = lane >> 4;
  const bf16* a0p = xb + (row0 + lr) * 512 + lg * 8;
  const bf16* a1p = a0p + 16 * 512;
  const bf16* b0p = Wt + (col0 + lr) * 512 + lg * 8;
  const bf16* b1p = b0p + 16 * 512;
  f32x4 acc00 = {0.f,0.f,0.f,0.f}, acc01 = acc00, acc10 = acc00, acc11 = acc00;
#pragma unroll
  for (int kk = 0; kk < 512; kk += 32) {
    bf16x8 a0 = *reinterpret_cast<const bf16x8*>(a0p + kk);
    bf16x8 a1 = *reinterpret_cast<const bf16x8*>(a1p + kk);
    bf16x8 b0 = *reinterpret_cast<const bf16x8*>(b0p + kk);
    bf16x8 b1 = *reinterpret_cast<const bf16x8*>(b1p + kk);
    acc00 = mfma_bf16(a0, b0, acc00);
    acc01 = mfma_bf16(a0, b1, acc01);
    acc10 = mfma_bf16(a1, b0, acc10);
    acc11 = mfma_bf16(a1, b1, acc11);
  }
#pragma unroll
  for (int ni = 0; ni < 2; ++ni) {
    int col = col0 + ni * 16 + lr;
    int wsel = col >> 9;
    int ncol = col & 511;
    int h = ncol >> 6, d = ncol & 63;
    const float* bias = wsel == 0 ? bq : (wsel == 1 ? bk : bv);
    float bval = bias[ncol];
#pragma unroll
    for (int mi = 0; mi < 2; ++mi) {
      f32x4 acc = (mi == 0) ? (ni == 0 ? acc00 : acc01) : (ni == 0 ? acc10 : acc11);
      int m0 = row0 + mi * 16 + lg * 4;
      int bidx = m0 >> 10, l0 = m0 & 1023;
      if (wsel == 2) {
        bf16x4 pv;
#pragma unroll
        for (int r = 0; r < 4; ++r) pv[r] = (bf16)(acc[r] + bval);
        *reinterpret_cast<bf16x4*>(vT + ((long)(bidx * H_ + h) * D_ + d) * L_ + l0) = pv;
      } else if (wsel == 0) {
#pragma unroll
        for (int r = 0; r < 4; ++r)
          qb[((long)(bidx * H_ + h) * L_ + l0 + r) * D_ + d] = (bf16)((acc[r] + bval) * 0.125f);
      } else {
#pragma unroll
        for (int r = 0; r < 4; ++r)
          kb[((long)(bidx * H_ + h) * L_ + l0 + r) * D_ + d] = (bf16)(acc[r] + bval);
      }
    }
  }
}

// ---------------- fused: z -> bias (LDS) -> attention partials, per (b, i-tile16, j-chunk64) ----------------
// 2048 blocks, 4 waves. Phase A: stream 256KB z slab, MFMA bias -> 16KB swizzled LDS.
// Phase B: swapped-operand QK (S: col=i, row=j), single-tile softmax, PV. fp16 partials.
__global__ __launch_bounds__(256) void fused_attn(
    const float* __restrict__ z, const bf16* __restrict__ qb, const bf16* __restrict__ kb,
    const bf16* __restrict__ vT, const bf16* __restrict__ Wtpb, const int* __restrict__ mask,
    _Float16* __restrict__ part_o, float* __restrict__ part_m, float* __restrict__ part_l) {
  __shared__ _Float16 bias_lds[8 * 16 * 64];   // [h][i][j], swizzled: X ^= ((i&7)<<4) ^ ((h&3)<<5)
  __shared__ bf16 p_lds[4][16 * 64];           // per wave, rows 128B, X ^= (i&7)<<4
  int bid = blockIdx.x;
  int jc = bid & 15, it = (bid >> 4) & 63, b = bid >> 10;
  int i0 = it * 16, j0 = jc * 64;
  int tid = threadIdx.x, w = tid >> 6, lane = tid & 63, lr = lane & 15, lg = lane >> 4;

  bf16x8 wb0 = *reinterpret_cast<const bf16x8*>(Wtpb + lr * 64 + lg * 8);
  bf16x8 wb1 = *reinterpret_cast<const bf16x8*>(Wtpb + lr * 64 + 32 + lg * 8);

  // ---------- phase A: bias for this (i-tile, j64), all 8 heads ----------
  {
    char* bl = (char*)bias_lds;
#pragma unroll
    for (int ii = 0; ii < 4; ++ii) {
      int i = w * 4 + ii;
      const float* zb_ = z + ((long)(b * L_ + i0 + i) * L_ + j0) * 64;
#pragma unroll
      for (int js = 0; js < 4; ++js) {
        const float* zr = zb_ + (js * 16 + lr) * 64 + lg * 8;
        f32x4 f0 = *reinterpret_cast<const f32x4*>(zr);
        f32x4 f1 = *reinterpret_cast<const f32x4*>(zr + 4);
        f32x4 f2 = *reinterpret_cast<const f32x4*>(zr + 32);
        f32x4 f3 = *reinterpret_cast<const f32x4*>(zr + 36);
        bf16x8 a0, a1;
#pragma unroll
        for (int e = 0; e < 4; ++e) {
          a0[e] = (bf16)f0[e]; a0[e + 4] = (bf16)f1[e];
          a1[e] = (bf16)f2[e]; a1[e + 4] = (bf16)f3[e];
        }
        f32x4 c = {0.f, 0.f, 0.f, 0.f};
        c = mfma_bf16(a0, wb0, c);
        c = mfma_bf16(a1, wb1, c);
        if (lr < 8) {                       // h = lr; lane holds 4 consecutive j (lg*4+r)
          f16x4 hv;
#pragma unroll
          for (int r = 0; r < 4; ++r) hv[r] = (_Float16)c[r];
          int X = (js * 32 + lg * 8) ^ ((i & 7) << 4) ^ ((lr & 3) << 5);
          *reinterpret_cast<f16x4*>(bl + lr * 2048 + i * 128 + X) = hv;
        }
      }
    }
  }
  __syncthreads();

  // ---------- phase B: attention, wave w handles heads 2w, 2w+1 ----------
  bool qok = mask[b * L_ + i0 + lr] != 0;
  char* pbuf = (char*)&p_lds[w][0];
  int swz = (lr & 7) << 4;
  const char* bl = (const char*)bias_lds;

#pragma unroll
  for (int hh = 0; hh < 2; ++hh) {
    int h = w * 2 + hh;
    const bf16* qrow = qb + ((long)(b * H_ + h) * L_ + i0 + lr) * D_ + lg * 8;
    bf16x8 qa0 = *reinterpret_cast<const bf16x8*>(qrow);        // B-frag: col=i, k=d
    bf16x8 qa1 = *reinterpret_cast<const bf16x8*>(qrow + 32);
    const bf16* kbase = kb + (long)(b * H_ + h) * L_ * D_;
    const bf16* vbase = vT + (long)(b * H_ + h) * D_ * L_;

    f32x4 s0, s1, s2, s3;
#pragma unroll
    for (int tile = 0; tile < 4; ++tile) {
      int X = (tile * 32 + lg * 8) ^ ((lr & 7) << 4) ^ ((h & 3) << 5);
      f16x4 bv = *reinterpret_cast<const f16x4*>(bl + h * 2048 + lr * 128 + X);
      f32x4 acc;
#pragma unroll
      for (int r = 0; r < 4; ++r) acc[r] = (float)bv[r];
      const bf16* kr = kbase + (long)(j0 + tile * 16 + lr) * D_ + lg * 8;   // A-frag: row=j
      acc = mfma_bf16(*reinterpret_cast<const bf16x8*>(kr), qa0, acc);
      acc = mfma_bf16(*reinterpret_cast<const bf16x8*>(kr + 32), qa1, acc);
      int4 mk = *reinterpret_cast<const int4*>(mask + b * L_ + j0 + tile * 16 + lg * 4);
      if (mk.x == 0) acc[0] = NEG_VAL;
      if (mk.y == 0) acc[1] = NEG_VAL;
      if (mk.z == 0) acc[2] = NEG_VAL;
      if (mk.w == 0) acc[3] = NEG_VAL;
      if (tile == 0) s0 = acc; else if (tile == 1) s1 = acc; else if (tile == 2) s2 = acc; else s3 = acc;
    }
    if (!qok) {
#pragma unroll
      for (int r = 0; r < 4; ++r) { s0[r] = NEG_VAL; s1[r] = NEG_VAL; s2[r] = NEG_VAL; s3[r] = NEG_VAL; }
    }
    // single-tile softmax over row i=lr (16 in-lane + lanes ^16, ^32)
    float m = s0[0];
#pragma unroll
    for (int r = 0; r < 4; ++r) m = fmaxf(fmaxf(fmaxf(m, s0[r]), fmaxf(s1[r], s2[r])), s3[r]);
    m = fmaxf(m, __shfl_xor(m, 16));
    m = fmaxf(m, __shfl_xor(m, 32));
    f32x4 p0, p1, p2, p3;
    float ps = 0.f;
#pragma unroll
    for (int r = 0; r < 4; ++r) {
      p0[r] = __expf(s0[r] - m); p1[r] = __expf(s1[r] - m);
      p2[r] = __expf(s2[r] - m); p3[r] = __expf(s3[r] - m);
      ps += p0[r] + p1[r] + p2[r] + p3[r];
    }
    ps += __shfl_xor(ps, 16);
    ps += __shfl_xor(ps, 32);
    // P -> p_lds (8B writes), then PV B-frags (16B reads)
#pragma unroll
    for (int tile = 0; tile < 4; ++tile) {
      f32x4 pv = (tile == 0) ? p0 : (tile == 1) ? p1 : (tile == 2) ? p2 : p3;
      bf16x4 pb_;
#pragma unroll
      for (int r = 0; r < 4; ++r) pb_[r] = (bf16)pv[r];
      *reinterpret_cast<bf16x4*>(pbuf + ((lr * 128 + tile * 32 + lg * 8) ^ swz)) = pb_;
    }
    bf16x8 pa0 = *reinterpret_cast<const bf16x8*>(pbuf + ((lr * 128 + lg * 16) ^ swz));
    bf16x8 pa1 = *reinterpret_cast<const bf16x8*>(pbuf + ((lr * 128 + 64 + lg * 16) ^ swz));
    long obase = ((long)bid * H_ + h) * 16;
#pragma unroll
    for (int dtile = 0; dtile < 4; ++dtile) {
      const bf16* vr = vbase + (long)(dtile * 16 + lr) * L_ + j0 + lg * 8;   // A-frag: row=d, k=j
      f32x4 acc = {0.f, 0.f, 0.f, 0.f};
      acc = mfma_bf16(*reinterpret_cast<const bf16x8*>(vr), pa0, acc);
      acc = mfma_bf16(*reinterpret_cast<const bf16x8*>(vr + 32), pa1, acc);
      f16x4 ov;
#pragma unroll
      for (int r = 0; r < 4; ++r) ov[r] = (_Float16)acc[r];
      *reinterpret_cast<f16x4*>(part_o + (obase + lr) * 64 + dtile * 16 + lg * 4) = ov;
    }
    if (lg == 0) { part_m[obase + lr] = m; part_l[obase + lr] = ps; }
  }
}

// ---------------- merge16: combine 16 j-chunk partials -> attn_out bf16 ----------------
__global__ __launch_bounds__(256) void merge16(
    const _Float16* __restrict__ part_o, const float* __restrict__ part_m,
    const float* __restrict__ part_l, bf16* __restrict__ attn_out) {
  int t = blockIdx.x * 256 + threadIdx.x;     // 262144 threads
  int d0 = (t & 15) * 4;
  int row = t >> 4;                            // (b,h,i)
  int b = row >> 13, h = (row >> 10) & 7, i = row & 1023;
  int it = i >> 4, il = i & 15;
  int bid0 = (b << 10) + (it << 4);
  float mv[16];
  float M = -3.0e38f;
#pragma unroll
  for (int p = 0; p < 16; ++p) {
    long base = ((long)(bid0 + p) * H_ + h) * 16 + il;
    mv[p] = part_m[base];
    M = fmaxf(M, mv[p]);
  }
  float lt = 0.f;
  float oa[4] = {0.f, 0.f, 0.f, 0.f};
#pragma unroll
  for (int p = 0; p < 16; ++p) {
    long base = ((long)(bid0 + p) * H_ + h) * 16 + il;
    float c = __expf(mv[p] - M);
    lt += c * part_l[base];
    f16x4 ov = *reinterpret_cast<const f16x4*>(part_o + base * 64 + d0);
#pragma unroll
    for (int e = 0; e < 4; ++e) oa[e] += c * (float)ov[e];
  }
  float inv = 1.0f / lt;
  bf16x4 r_;
#pragma unroll
  for (int e = 0; e < 4; ++e) r_[e] = (bf16)(oa[e] * inv);
  *reinterpret_cast<bf16x4*>(attn_out + ((long)(b * L_ + i)) * DM_ + h * D_ + d0) = r_;
}

// ---------------- out: attn_out(2048x512) @ Wto^T -> d_out fp32 + bo ----------------
__global__ __launch_bounds__(256) void out_gemm(
    const bf16* __restrict__ ab, const bf16* __restrict__ Wto,
    const float* __restrict__ bo, float* __restrict__ out) {
  int wid = blockIdx.x * 4 + (threadIdx.x >> 6);
  int lane = threadIdx.x & 63;
  int mt = wid >> 4, nt = wid & 15;    // 64 x 16 tiles of 32x32
  int row0 = mt * 32, col0 = nt * 32;
  int lr = lane & 15, lg = lane >> 4;
  const bf16* a0p = ab + (row0 + lr) * 512 + lg * 8;
  const bf16* a1p = a0p + 16 * 512;
  const bf16* b0p = Wto + (col0 + lr) * 512 + lg * 8;
  const bf16* b1p = b0p + 16 * 512;
  f32x4 acc00 = {0.f,0.f,0.f,0.f}, acc01 = acc00, acc10 = acc00, acc11 = acc00;
#pragma unroll
  for (int kk = 0; kk < 512; kk += 32) {
    bf16x8 a0 = *reinterpret_cast<const bf16x8*>(a0p + kk);
    bf16x8 a1 = *reinterpret_cast<const bf16x8*>(a1p + kk);
    bf16x8 b0 = *reinterpret_cast<const bf16x8*>(b0p + kk);
    bf16x8 b1 = *reinterpret_cast<const bf16x8*>(b1p + kk);
    acc00 = mfma_bf16(a0, b0, acc00);
    acc01 = mfma_bf16(a0, b1, acc01);
    acc10 = mfma_bf16(a1, b0, acc10);
    acc11 = mfma_bf16(a1, b1, acc11);
  }
#pragma unroll
  for (int ni = 0; ni < 2; ++ni) {
    int col = col0 + ni * 16 + lr;
    float bval = bo[col];
#pragma unroll
    for (int mi = 0; mi < 2; ++mi) {
      f32x4 acc = (mi == 0) ? (ni == 0 ? acc00 : acc01) : (ni == 0 ? acc10 : acc11);
      int m0 = row0 + mi * 16 + lg * 4;
#pragma unroll
      for (int r = 0; r < 4; ++r) out[(long)(m0 + r) * 512 + col] = acc[r] + bval;
    }
  }
}

extern "C" void kernel_launch(void* const* d_in, const int* in_sizes, int n_in,
                              void* d_out, int out_size, void* d_ws, size_t ws_size,
                              hipStream_t stream) {
  const float* x    = (const float*)d_in[0];
  const float* z    = (const float*)d_in[1];
  const int*   mask = (const int*)d_in[2];
  const float* Wq   = (const float*)d_in[3];
  const float* bq   = (const float*)d_in[4];
  const float* Wk   = (const float*)d_in[5];
  const float* bk   = (const float*)d_in[6];
  const float* Wv   = (const float*)d_in[7];
  const float* bv   = (const float*)d_in[8];
  const float* Wo   = (const float*)d_in[9];
  const float* bo   = (const float*)d_in[10];
  const float* Wpb  = (const float*)d_in[11];

  char* ws = (char*)d_ws;
  bf16* xb        = (bf16*)(ws + 0);                    // 2 MB
  bf16* Wt        = (bf16*)(ws + 2097152);              // 1.5 MB
  bf16* Wto       = (bf16*)(ws + 3670016);              // 0.5 MB
  bf16* Wtpb      = (bf16*)(ws + 4194304);              // 2 KB
  bf16* qbuf      = (bf16*)(ws + 4196352);              // 2 MB
  bf16* kbuf      = (bf16*)(ws + 6293504);              // 2 MB
  bf16* vTbuf     = (bf16*)(ws + 8390656);              // 2 MB
  bf16* attn_out  = (bf16*)(ws + 10487808);             // 2 MB
  _Float16* part_o = (_Float16*)(ws + 12584960);        // 33.5 MB (2048*8*16*64 fp16)
  float* part_m   = (float*)(ws + 46139392);            // 1 MB
  float* part_l   = (float*)(ws + 47187968);            // 1 MB

  prep_kernel<<<2048, 256, 0, stream>>>(x, Wq, Wk, Wv, Wo, Wpb, xb, Wt, Wto, Wtpb);
  qkv_gemm<<<768, 256, 0, stream>>>(xb, Wt, bq, bk, bv, qbuf, kbuf, vTbuf);
  fused_attn<<<2048, 256, 0, stream>>>(z, qbuf, kbuf, vTbuf, Wtpb, mask, part_o, part_m, part_l);
  merge16<<<1024, 256, 0, stream>>>(part_o, part_m, part_l, attn_out);
  out_gemm<<<256, 256, 0, stream>>>(attn_out, Wto, bo, (float*)d_out);
}

// Round 11
// 187.440 us; speedup vs baseline: 17.6449x; 1.0056x over previous
//
#include <hip/hip_runtime.h>

typedef __bf16 bf16;
typedef __attribute__((ext_vector_type(4))) __bf16 bf16x4;
typedef __attribute__((ext_vector_type(8))) __bf16 bf16x8;
typedef __attribute__((ext_vector_type(4))) float f32x4;
typedef __attribute__((ext_vector_type(4))) _Float16 f16x4;
typedef __attribute__((ext_vector_type(2))) _Float16 f16x2;

#define B_   2
#define L_   1024
#define DM_  512
#define H_   8
#define D_   64
#define PD_  64
#define NEG_VAL -10000.0f

#define XB_N   (2048*512)
#define WT_N   (1536*512)
#define WTO_N  (512*512)
#define WTPB_N (16*64)

static __device__ __forceinline__ f32x4 mfma_bf16(bf16x8 a, bf16x8 b, f32x4 c) {
  return __builtin_amdgcn_mfma_f32_16x16x32_bf16(a, b, c, 0, 0, 0);
}

// ---------------- prep: convert & transpose weights, convert x ----------------
__global__ __launch_bounds__(256) void prep_kernel(
    const float* __restrict__ x, const float* __restrict__ Wq, const float* __restrict__ Wk,
    const float* __restrict__ Wv, const float* __restrict__ Wo, const float* __restrict__ Wpb,
    bf16* __restrict__ xb, bf16* __restrict__ Wt, bf16* __restrict__ Wto, bf16* __restrict__ Wtpb) {
  const int total = XB_N + WT_N + WTO_N + WTPB_N;
  for (int idx = blockIdx.x * 256 + threadIdx.x; idx < total; idx += gridDim.x * 256) {
    if (idx < XB_N) {
      xb[idx] = (bf16)x[idx];
    } else if (idx < XB_N + WT_N) {
      int t = idx - XB_N;
      int n = t >> 9, kk = t & 511;       // Wt[n][k]
      int sel = n >> 9, nn = n & 511;
      const float* W = sel == 0 ? Wq : (sel == 1 ? Wk : Wv);
      Wt[t] = (bf16)W[kk * 512 + nn];
    } else if (idx < XB_N + WT_N + WTO_N) {
      int t = idx - XB_N - WT_N;
      int n = t >> 9, kk = t & 511;
      Wto[t] = (bf16)Wo[kk * 512 + n];
    } else {
      int t = idx - XB_N - WT_N - WTO_N;
      int n = t >> 6, kk = t & 63;
      Wtpb[t] = (n < 8) ? (bf16)Wpb[kk * 8 + n] : (bf16)0.0f;
    }
  }
}

// ---------------- qkv: xb(2048x512) @ Wt^T -> q,k bf16 [b][h][l][d], vT bf16 [b][h][d][l] ----------------
__global__ __launch_bounds__(256) void qkv_gemm(
    const bf16* __restrict__ xb, const bf16* __restrict__ Wt,
    const float* __restrict__ bq, const float* __restrict__ bk, const float* __restrict__ bv,
    bf16* __restrict__ qb, bf16* __restrict__ kb, bf16* __restrict__ vT) {
  int wid = blockIdx.x * 4 + (threadIdx.x >> 6);
  int lane = threadIdx.x & 63;
  int mt = wid / 48, nt = wid - mt * 48;   // 64 x 48 tiles of 32x32
  int row0 = mt * 32, col0 = nt * 32;
  int lr = lane & 15, lg = lane >> 4;
  const bf16* a0p = xb + (row0 + lr) * 512 + lg * 8;
  const bf16* a1p = a0p + 16 * 512;
  const bf16* b0p = Wt + (col0 + lr) * 512 + lg * 8;
  const bf16* b1p = b0p + 16 * 512;
  f32x4 acc00 = {0.f,0.f,0.f,0.f}, acc01 = acc00, acc10 = acc00, acc11 = acc00;
#pragma unroll
  for (int kk = 0; kk < 512; kk += 32) {
    bf16x8 a0 = *reinterpret_cast<const bf16x8*>(a0p + kk);
    bf16x8 a1 = *reinterpret_cast<const bf16x8*>(a1p + kk);
    bf16x8 b0 = *reinterpret_cast<const bf16x8*>(b0p + kk);
    bf16x8 b1 = *reinterpret_cast<const bf16x8*>(b1p + kk);
    acc00 = mfma_bf16(a0, b0, acc00);
    acc01 = mfma_bf16(a0, b1, acc01);
    acc10 = mfma_bf16(a1, b0, acc10);
    acc11 = mfma_bf16(a1, b1, acc11);
  }
#pragma unroll
  for (int ni = 0; ni < 2; ++ni) {
    int col = col0 + ni * 16 + lr;
    int wsel = col >> 9;
    int ncol = col & 511;
    int h = ncol >> 6, d = ncol & 63;
    const float* bias = wsel == 0 ? bq : (wsel == 1 ? bk : bv);
    float bval = bias[ncol];
#pragma unroll
    for (int mi = 0; mi < 2; ++mi) {
      f32x4 acc = (mi == 0) ? (ni == 0 ? acc00 : acc01) : (ni == 0 ? acc10 : acc11);
      int m0 = row0 + mi * 16 + lg * 4;
      int bidx = m0 >> 10, l0 = m0 & 1023;
      if (wsel == 2) {
        bf16x4 pv;
#pragma unroll
        for (int r = 0; r < 4; ++r) pv[r] = (bf16)(acc[r] + bval);
        *reinterpret_cast<bf16x4*>(vT + ((long)(bidx * H_ + h) * D_ + d) * L_ + l0) = pv;
      } else if (wsel == 0) {
#pragma unroll
        for (int r = 0; r < 4; ++r)
          qb[((long)(bidx * H_ + h) * L_ + l0 + r) * D_ + d] = (bf16)((acc[r] + bval) * 0.125f);
      } else {
#pragma unroll
        for (int r = 0; r < 4; ++r)
          kb[((long)(bidx * H_ + h) * L_ + l0 + r) * D_ + d] = (bf16)(acc[r] + bval);
      }
    }
  }
}

// ---------------- fused producer/consumer: z -> bias (dbuf LDS) || attention partials ----------------
// grid 512: jg=bid&3 (j-quad), it=(bid>>2)&63, b=bid>>8. 8 waves: 0-3 produce bias for
// chunk t+1 while 4-7 consume chunk t (2 heads/wave). One barrier per chunk.
__global__ __launch_bounds__(512) void fused_attn(
    const float* __restrict__ z, const bf16* __restrict__ qb, const bf16* __restrict__ kb,
    const bf16* __restrict__ vT, const bf16* __restrict__ Wtpb, const int* __restrict__ mask,
    _Float16* __restrict__ part_o, float* __restrict__ part_m, float* __restrict__ part_l) {
  __shared__ _Float16 bias_lds[2][8 * 16 * 64];  // [buf][h][i][j], X ^= ((i&7)<<4) ^ ((h&3)<<5)
  __shared__ bf16 p_lds[4][16 * 64];             // per consumer wave
  int bid = blockIdx.x;
  int jg = bid & 3, it = (bid >> 2) & 63, b = bid >> 8;
  int i0 = it * 16;
  int tid = threadIdx.x, w = tid >> 6, lane = tid & 63, lr = lane & 15, lg = lane >> 4;
  bool producer = w < 4;

  if (producer) {
    int pw = w;
    bf16x8 wb0 = *reinterpret_cast<const bf16x8*>(Wtpb + lr * 64 + lg * 8);
    bf16x8 wb1 = *reinterpret_cast<const bf16x8*>(Wtpb + lr * 64 + 32 + lg * 8);
    // produce chunk 0
    {
      char* bl = (char*)&bias_lds[0][0];
      int j0 = jg * 256;
#pragma unroll
      for (int ii = 0; ii < 4; ++ii) {
        int i = pw * 4 + ii;
        const float* zb_ = z + ((long)(b * L_ + i0 + i) * L_ + j0) * 64;
#pragma unroll
        for (int js = 0; js < 4; ++js) {
          const float* zr = zb_ + (js * 16 + lr) * 64 + lg * 8;
          f32x4 f0 = *reinterpret_cast<const f32x4*>(zr);
          f32x4 f1 = *reinterpret_cast<const f32x4*>(zr + 4);
          f32x4 f2 = *reinterpret_cast<const f32x4*>(zr + 32);
          f32x4 f3 = *reinterpret_cast<const f32x4*>(zr + 36);
          bf16x8 a0, a1;
#pragma unroll
          for (int e = 0; e < 4; ++e) {
            a0[e] = (bf16)f0[e]; a0[e + 4] = (bf16)f1[e];
            a1[e] = (bf16)f2[e]; a1[e + 4] = (bf16)f3[e];
          }
          f32x4 c = {0.f, 0.f, 0.f, 0.f};
          c = mfma_bf16(a0, wb0, c);
          c = mfma_bf16(a1, wb1, c);
          if (lr < 8) {
            f16x4 hv;
#pragma unroll
            for (int r = 0; r < 4; ++r) hv[r] = (_Float16)c[r];
            int X = (js * 32 + lg * 8) ^ ((i & 7) << 4) ^ ((lr & 3) << 5);
            *reinterpret_cast<f16x4*>(bl + lr * 2048 + i * 128 + X) = hv;
          }
        }
      }
    }
    for (int t = 0; t < 4; ++t) {
      __syncthreads();
      if (t < 3) {
        char* bl = (char*)&bias_lds[(t + 1) & 1][0];
        int j0 = (jg * 4 + t + 1) * 64;
#pragma unroll
        for (int ii = 0; ii < 4; ++ii) {
          int i = pw * 4 + ii;
          const float* zb_ = z + ((long)(b * L_ + i0 + i) * L_ + j0) * 64;
#pragma unroll
          for (int js = 0; js < 4; ++js) {
            const float* zr = zb_ + (js * 16 + lr) * 64 + lg * 8;
            f32x4 f0 = *reinterpret_cast<const f32x4*>(zr);
            f32x4 f1 = *reinterpret_cast<const f32x4*>(zr + 4);
            f32x4 f2 = *reinterpret_cast<const f32x4*>(zr + 32);
            f32x4 f3 = *reinterpret_cast<const f32x4*>(zr + 36);
            bf16x8 a0, a1;
#pragma unroll
            for (int e = 0; e < 4; ++e) {
              a0[e] = (bf16)f0[e]; a0[e + 4] = (bf16)f1[e];
              a1[e] = (bf16)f2[e]; a1[e + 4] = (bf16)f3[e];
            }
            f32x4 c = {0.f, 0.f, 0.f, 0.f};
            c = mfma_bf16(a0, wb0, c);
            c = mfma_bf16(a1, wb1, c);
            if (lr < 8) {
              f16x4 hv;
#pragma unroll
              for (int r = 0; r < 4; ++r) hv[r] = (_Float16)c[r];
              int X = (js * 32 + lg * 8) ^ ((i & 7) << 4) ^ ((lr & 3) << 5);
              *reinterpret_cast<f16x4*>(bl + lr * 2048 + i * 128 + X) = hv;
            }
          }
        }
      }
    }
  } else {
    int cw = w - 4;
    bool qok = mask[b * L_ + i0 + lr] != 0;
    char* pbuf = (char*)&p_lds[cw][0];
    int swz = (lr & 7) << 4;
    // hoist per-head invariants (heads 2cw, 2cw+1)
    const bf16* qrow0 = qb + ((long)(b * H_ + cw * 2) * L_ + i0 + lr) * D_ + lg * 8;
    const bf16* qrow1 = qb + ((long)(b * H_ + cw * 2 + 1) * L_ + i0 + lr) * D_ + lg * 8;
    bf16x8 qa00 = *reinterpret_cast<const bf16x8*>(qrow0);
    bf16x8 qa01 = *reinterpret_cast<const bf16x8*>(qrow0 + 32);
    bf16x8 qa10 = *reinterpret_cast<const bf16x8*>(qrow1);
    bf16x8 qa11 = *reinterpret_cast<const bf16x8*>(qrow1 + 32);
    for (int t = 0; t < 4; ++t) {
      __syncthreads();
      int j0 = (jg * 4 + t) * 64;
      long cid = ((long)(b * 64 + it) << 4) + jg * 4 + t;
      const char* bl = (const char*)&bias_lds[t & 1][0];
#pragma unroll
      for (int hh = 0; hh < 2; ++hh) {
        int h = cw * 2 + hh;
        bf16x8 qa0 = hh == 0 ? qa00 : qa10;
        bf16x8 qa1 = hh == 0 ? qa01 : qa11;
        const bf16* kbase = kb + (long)(b * H_ + h) * L_ * D_;
        const bf16* vbase = vT + (long)(b * H_ + h) * D_ * L_;
        f32x4 s0, s1, s2, s3;
#pragma unroll
        for (int tile = 0; tile < 4; ++tile) {
          int X = (tile * 32 + lg * 8) ^ ((lr & 7) << 4) ^ ((h & 3) << 5);
          f16x4 bv = *reinterpret_cast<const f16x4*>(bl + h * 2048 + lr * 128 + X);
          f32x4 acc;
#pragma unroll
          for (int r = 0; r < 4; ++r) acc[r] = (float)bv[r];
          const bf16* kr = kbase + (long)(j0 + tile * 16 + lr) * D_ + lg * 8;
          acc = mfma_bf16(*reinterpret_cast<const bf16x8*>(kr), qa0, acc);
          acc = mfma_bf16(*reinterpret_cast<const bf16x8*>(kr + 32), qa1, acc);
          int4 mk = *reinterpret_cast<const int4*>(mask + b * L_ + j0 + tile * 16 + lg * 4);
          if (mk.x == 0) acc[0] = NEG_VAL;
          if (mk.y == 0) acc[1] = NEG_VAL;
          if (mk.z == 0) acc[2] = NEG_VAL;
          if (mk.w == 0) acc[3] = NEG_VAL;
          if (tile == 0) s0 = acc; else if (tile == 1) s1 = acc; else if (tile == 2) s2 = acc; else s3 = acc;
        }
        if (!qok) {
#pragma unroll
          for (int r = 0; r < 4; ++r) { s0[r] = NEG_VAL; s1[r] = NEG_VAL; s2[r] = NEG_VAL; s3[r] = NEG_VAL; }
        }
        float m = s0[0];
#pragma unroll
        for (int r = 0; r < 4; ++r) m = fmaxf(fmaxf(fmaxf(m, s0[r]), fmaxf(s1[r], s2[r])), s3[r]);
        m = fmaxf(m, __shfl_xor(m, 16));
        m = fmaxf(m, __shfl_xor(m, 32));
        f32x4 p0, p1, p2, p3;
        float ps = 0.f;
#pragma unroll
        for (int r = 0; r < 4; ++r) {
          p0[r] = __expf(s0[r] - m); p1[r] = __expf(s1[r] - m);
          p2[r] = __expf(s2[r] - m); p3[r] = __expf(s3[r] - m);
          ps += p0[r] + p1[r] + p2[r] + p3[r];
        }
        ps += __shfl_xor(ps, 16);
        ps += __shfl_xor(ps, 32);
#pragma unroll
        for (int tile = 0; tile < 4; ++tile) {
          f32x4 pv = (tile == 0) ? p0 : (tile == 1) ? p1 : (tile == 2) ? p2 : p3;
          bf16x4 pb_;
#pragma unroll
          for (int r = 0; r < 4; ++r) pb_[r] = (bf16)pv[r];
          *reinterpret_cast<bf16x4*>(pbuf + ((lr * 128 + tile * 32 + lg * 8) ^ swz)) = pb_;
        }
        bf16x8 pa0 = *reinterpret_cast<const bf16x8*>(pbuf + ((lr * 128 + lg * 16) ^ swz));
        bf16x8 pa1 = *reinterpret_cast<const bf16x8*>(pbuf + ((lr * 128 + 64 + lg * 16) ^ swz));
        long obase = (cid * H_ + h) * 16;
#pragma unroll
        for (int dtile = 0; dtile < 4; ++dtile) {
          const bf16* vr = vbase + (long)(dtile * 16 + lr) * L_ + j0 + lg * 8;
          f32x4 acc = {0.f, 0.f, 0.f, 0.f};
          acc = mfma_bf16(*reinterpret_cast<const bf16x8*>(vr), pa0, acc);
          acc = mfma_bf16(*reinterpret_cast<const bf16x8*>(vr + 32), pa1, acc);
          f16x4 ov;
#pragma unroll
          for (int r = 0; r < 4; ++r) ov[r] = (_Float16)acc[r];
          *reinterpret_cast<f16x4*>(part_o + (obase + lr) * 64 + dtile * 16 + lg * 4) = ov;
        }
        if (lg == 0) { part_m[obase + lr] = m; part_l[obase + lr] = ps; }
      }
    }
  }
}

// ---------------- merge16: combine 16 j-chunk partials -> attn_out bf16 ----------------
__global__ __launch_bounds__(256) void merge16(
    const _Float16* __restrict__ part_o, const float* __restrict__ part_m,
    const float* __restrict__ part_l, bf16* __restrict__ attn_out) {
  int t = blockIdx.x * 256 + threadIdx.x;     // 262144 threads
  int d0 = (t & 15) * 4;
  int row = t >> 4;                            // (b,h,i)
  int b = row >> 13, h = (row >> 10) & 7, i = row & 1023;
  int it = i >> 4, il = i & 15;
  int bid0 = (b << 10) + (it << 4);
  float mv[16];
  float M = -3.0e38f;
#pragma unroll
  for (int p = 0; p < 16; ++p) {
    long base = ((long)(bid0 + p) * H_ + h) * 16 + il;
    mv[p] = part_m[base];
    M = fmaxf(M, mv[p]);
  }
  float lt = 0.f;
  float oa[4] = {0.f, 0.f, 0.f, 0.f};
#pragma unroll
  for (int p = 0; p < 16; ++p) {
    long base = ((long)(bid0 + p) * H_ + h) * 16 + il;
    float c = __expf(mv[p] - M);
    lt += c * part_l[base];
    f16x4 ov = *reinterpret_cast<const f16x4*>(part_o + base * 64 + d0);
#pragma unroll
    for (int e = 0; e < 4; ++e) oa[e] += c * (float)ov[e];
  }
  float inv = 1.0f / lt;
  bf16x4 r_;
#pragma unroll
  for (int e = 0; e < 4; ++e) r_[e] = (bf16)(oa[e] * inv);
  *reinterpret_cast<bf16x4*>(attn_out + ((long)(b * L_ + i)) * DM_ + h * D_ + d0) = r_;
}

// ---------------- out: attn_out(2048x512) @ Wto^T -> d_out fp32 + bo ----------------
__global__ __launch_bounds__(256) void out_gemm(
    const bf16* __restrict__ ab, const bf16* __restrict__ Wto,
    const float* __restrict__ bo, float* __restrict__ out) {
  int wid = blockIdx.x * 4 + (threadIdx.x >> 6);
  int lane = threadIdx.x & 63;
  int mt = wid >> 4, nt = wid & 15;    // 64 x 16 tiles of 32x32
  int row0 = mt * 32, col0 = nt * 32;
  int lr = lane & 15, lg = lane >> 4;
  const bf16* a0p = ab + (row0 + lr) * 512 + lg * 8;
  const bf16* a1p = a0p + 16 * 512;
  const bf16* b0p = Wto + (col0 + lr) * 512 + lg * 8;
  const bf16* b1p = b0p + 16 * 512;
  f32x4 acc00 = {0.f,0.f,0.f,0.f}, acc01 = acc00, acc10 = acc00, acc11 = acc00;
#pragma unroll
  for (int kk = 0; kk < 512; kk += 32) {
    bf16x8 a0 = *reinterpret_cast<const bf16x8*>(a0p + kk);
    bf16x8 a1 = *reinterpret_cast<const bf16x8*>(a1p + kk);
    bf16x8 b0 = *reinterpret_cast<const bf16x8*>(b0p + kk);
    bf16x8 b1 = *reinterpret_cast<const bf16x8*>(b1p + kk);
    acc00 = mfma_bf16(a0, b0, acc00);
    acc01 = mfma_bf16(a0, b1, acc01);
    acc10 = mfma_bf16(a1, b0, acc10);
    acc11 = mfma_bf16(a1, b1, acc11);
  }
#pragma unroll
  for (int ni = 0; ni < 2; ++ni) {
    int col = col0 + ni * 16 + lr;
    float bval = bo[col];
#pragma unroll
    for (int mi = 0; mi < 2; ++mi) {
      f32x4 acc = (mi == 0) ? (ni == 0 ? acc00 : acc01) : (ni == 0 ? acc10 : acc11);
      int m0 = row0 + mi * 16 + lg * 4;
#pragma unroll
      for (int r = 0; r < 4; ++r) out[(long)(m0 + r) * 512 + col] = acc[r] + bval;
    }
  }
}

extern "C" void kernel_launch(void* const* d_in, const int* in_sizes, int n_in,
                              void* d_out, int out_size, void* d_ws, size_t ws_size,
                              hipStream_t stream) {
  const float* x    = (const float*)d_in[0];
  const float* z    = (const float*)d_in[1];
  const int*   mask = (const int*)d_in[2];
  const float* Wq   = (const float*)d_in[3];
  const float* bq   = (const float*)d_in[4];
  const float* Wk   = (const float*)d_in[5];
  const float* bk   = (const float*)d_in[6];
  const float* Wv   = (const float*)d_in[7];
  const float* bv   = (const float*)d_in[8];
  const float* Wo   = (const float*)d_in[9];
  const float* bo   = (const float*)d_in[10];
  const float* Wpb  = (const float*)d_in[11];

  char* ws = (char*)d_ws;
  bf16* xb        = (bf16*)(ws + 0);                    // 2 MB
  bf16* Wt        = (bf16*)(ws + 2097152);              // 1.5 MB
  bf16* Wto       = (bf16*)(ws + 3670016);              // 0.5 MB
  bf16* Wtpb      = (bf16*)(ws + 4194304);              // 2 KB
  bf16* qbuf      = (bf16*)(ws + 4196352);              // 2 MB
  bf16* kbuf      = (bf16*)(ws + 6293504);              // 2 MB
  bf16* vTbuf     = (bf16*)(ws + 8390656);              // 2 MB
  bf16* attn_out  = (bf16*)(ws + 10487808);             // 2 MB
  _Float16* part_o = (_Float16*)(ws + 12584960);        // 33.5 MB (2048*8*16*64 fp16)
  float* part_m   = (float*)(ws + 46139392);            // 1 MB
  float* part_l   = (float*)(ws + 47187968);            // 1 MB

  prep_kernel<<<2048, 256, 0, stream>>>(x, Wq, Wk, Wv, Wo, Wpb, xb, Wt, Wto, Wtpb);
  qkv_gemm<<<768, 256, 0, stream>>>(xb, Wt, bq, bk, bv, qbuf, kbuf, vTbuf);
  fused_attn<<<512, 512, 0, stream>>>(z, qbuf, kbuf, vTbuf, Wtpb, mask, part_o, part_m, part_l);
  merge16<<<1024, 256, 0, stream>>>(part_o, part_m, part_l, attn_out);
  out_gemm<<<256, 256, 0, stream>>>(attn_out, Wto, bo, (float*)d_out);
}